// Round 1
// baseline (11.638 us; speedup 1.0000x reference)
//
#include <hip/hip_runtime.h>

// Problem constants (reference: B=2048, D=512, float32 in/out).
#define BB 2048
#define DD 512
#define ROWS_PER_BLOCK 4          // 4 waves * 64 lanes = 256 threads
#define NBLOCKS (BB / ROWS_PER_BLOCK)  // 512

__device__ __forceinline__ float wred_max(float v) {
#pragma unroll
    for (int off = 32; off; off >>= 1) v = fmaxf(v, __shfl_xor(v, off));
    return v;
}

__device__ __forceinline__ float wred_sum(float v) {
#pragma unroll
    for (int off = 32; off; off >>= 1) v += __shfl_xor(v, off);
    return v;
}

// Per-wave: sum_d softmax(row)_d^2 for one row of D=512 floats.
// Each of 64 lanes handles 8 contiguous floats (two float4 loads).
__device__ __forceinline__ float row_softmax_sumsq(const float* __restrict__ row, int lane) {
    const float4* p = reinterpret_cast<const float4*>(row + lane * 8);
    float4 a = p[0];
    float4 b = p[1];

    float m = fmaxf(fmaxf(fmaxf(a.x, a.y), fmaxf(a.z, a.w)),
                    fmaxf(fmaxf(b.x, b.y), fmaxf(b.z, b.w)));
    m = wred_max(m);

    float e0 = __expf(a.x - m), e1 = __expf(a.y - m), e2 = __expf(a.z - m), e3 = __expf(a.w - m);
    float e4 = __expf(b.x - m), e5 = __expf(b.y - m), e6 = __expf(b.z - m), e7 = __expf(b.w - m);

    float s1 = (e0 + e1) + (e2 + e3) + ((e4 + e5) + (e6 + e7));
    float s2 = (e0 * e0 + e1 * e1) + (e2 * e2 + e3 * e3) +
               ((e4 * e4 + e5 * e5) + (e6 * e6 + e7 * e7));

    s1 = wred_sum(s1);
    s2 = wred_sum(s2);

    // sum p^2 = sum e^2 / (sum e)^2
    return s2 / (s1 * s1);
}

__global__ __launch_bounds__(256) void emi_stage1(const float* __restrict__ X,
                                                  const float* __restrict__ Y,
                                                  double* __restrict__ partials) {
    const int wave = threadIdx.x >> 6;
    const int lane = threadIdx.x & 63;
    const int row  = blockIdx.x * ROWS_PER_BLOCK + wave;

    const float sx = row_softmax_sumsq(X + (size_t)row * DD, lane);
    const float sy = row_softmax_sumsq(Y + (size_t)row * DD, lane);

    __shared__ float lsx[ROWS_PER_BLOCK];
    __shared__ float lsy[ROWS_PER_BLOCK];
    if (lane == 0) { lsx[wave] = sx; lsy[wave] = sy; }
    __syncthreads();

    if (threadIdx.x == 0) {
        double ax = 0.0, ay = 0.0, axy = 0.0;
#pragma unroll
        for (int i = 0; i < ROWS_PER_BLOCK; ++i) {
            ax  += (double)lsx[i];
            ay  += (double)lsy[i];
            axy += (double)lsx[i] * (double)lsy[i];
        }
        partials[blockIdx.x * 3 + 0] = ax;
        partials[blockIdx.x * 3 + 1] = ay;
        partials[blockIdx.x * 3 + 2] = axy;
    }
}

__global__ __launch_bounds__(512) void emi_stage2(const double* __restrict__ partials,
                                                  float* __restrict__ out) {
    __shared__ double sx[NBLOCKS];
    __shared__ double sy[NBLOCKS];
    __shared__ double sxy[NBLOCKS];

    const int t = threadIdx.x;
    sx[t]  = partials[t * 3 + 0];
    sy[t]  = partials[t * 3 + 1];
    sxy[t] = partials[t * 3 + 2];
    __syncthreads();

    // Deterministic tree reduction.
#pragma unroll
    for (int s = NBLOCKS / 2; s > 0; s >>= 1) {
        if (t < s) {
            sx[t]  += sx[t + s];
            sy[t]  += sy[t + s];
            sxy[t] += sxy[t + s];
        }
        __syncthreads();
    }

    if (t == 0) {
        const double invB = 1.0 / (double)BB;
        out[0] = (float)(-sx[0] * invB);
        out[1] = (float)(-sy[0] * invB);
        out[2] = (float)(sxy[0] * invB);
    }
}

extern "C" void kernel_launch(void* const* d_in, const int* in_sizes, int n_in,
                              void* d_out, int out_size, void* d_ws, size_t ws_size,
                              hipStream_t stream) {
    const float* X = (const float*)d_in[0];
    const float* Y = (const float*)d_in[1];
    float* out = (float*)d_out;
    double* partials = (double*)d_ws;  // NBLOCKS * 3 doubles = 12 KiB

    emi_stage1<<<NBLOCKS, 256, 0, stream>>>(X, Y, partials);
    emi_stage2<<<1, NBLOCKS, 0, stream>>>(partials, out);
}